// Round 5
// baseline (105.787 us; speedup 1.0000x reference)
//
#include <hip/hip_runtime.h>

// B=8, S=1024, D=256, H=16, HD=16. Rows G = B*S = 8192.
#define Gz 8192
#define Dz 256
#define Sz 1024

typedef _Float16 half8 __attribute__((ext_vector_type(8)));
typedef float    floatx4 __attribute__((ext_vector_type(4)));

// width-16 async global->LDS (LDS dest must be wave-uniform base + lane*16)
#define GLOAD_LDS(gptr, lptr)                                                      \
    __builtin_amdgcn_global_load_lds(                                              \
        (const __attribute__((address_space(1))) void*)(gptr),                     \
        (__attribute__((address_space(3))) void*)(lptr), 16, 0, 0)

__device__ inline half8 cvt8(const float* __restrict__ p) {
    float4 a = ((const float4*)p)[0];
    float4 b = ((const float4*)p)[1];
    half8 h;
    h[0]=(_Float16)a.x; h[1]=(_Float16)a.y; h[2]=(_Float16)a.z; h[3]=(_Float16)a.w;
    h[4]=(_Float16)b.x; h[5]=(_Float16)b.y; h[6]=(_Float16)b.z; h[7]=(_Float16)b.w;
    return h;
}

// ---------------------------------------------------------------------------
// K0: x -> fp16 x16 [8192x256]; pack [Wq;Wv] -> fp16 w16 [512x256].
// ---------------------------------------------------------------------------
__global__ __launch_bounds__(256) void convert_kernel(
    const float* __restrict__ x, const float* __restrict__ wq,
    const float* __restrict__ wv,
    _Float16* __restrict__ x16, _Float16* __restrict__ w16)
{
    size_t e = ((size_t)blockIdx.x * 256 + threadIdx.x) * 8;
    const float* src;
    _Float16* dst;
    if (e < (size_t)Gz * Dz) { src = x + e; dst = x16 + e; }
    else {
        size_t e2 = e - (size_t)Gz * Dz;        // 0 .. 131071
        dst = w16 + e2;
        src = (e2 < 65536) ? (wq + e2) : (wv + (e2 - 65536));
    }
    *(half8*)dst = cvt8(src);
}

// ---------------------------------------------------------------------------
// K1: C[8192x512] = x16 @ w16^T, +bias, RoPE, fp16 -> xq (by<2) / xv (by>=2).
// 128x128 tile, BK=64, global_load_lds width16, 4 waves each 64x64.
// (verbatim from the round-3 PASSED kernel)
// ---------------------------------------------------------------------------
__global__ __launch_bounds__(256) void qv_gemm_rope(
    const _Float16* __restrict__ x16, const _Float16* __restrict__ w16,
    const float* __restrict__ bq, const float* __restrict__ bv,
    _Float16* __restrict__ xq, _Float16* __restrict__ xv)
{
    __shared__ _Float16 As[128 * 64];   // unpadded: global_load_lds layout
    __shared__ _Float16 Bs[128 * 64];
    const int t = threadIdx.x, lane = t & 63, w = t >> 6;
    const int g0 = blockIdx.x * 128;
    const int by = blockIdx.y;              // 0..3 -> cols [by*128, +128)
    const int n0 = by * 128;
    const int wm = (w >> 1) * 64, wn = (w & 1) * 64;
    const int fr = lane & 15, kq = lane >> 4;

    floatx4 acc[4][4] = {};

    for (int k0 = 0; k0 < Dz; k0 += 64) {
        __syncthreads();
        #pragma unroll
        for (int p = 0; p < 4; ++p) {
            const int flat = (t + 256 * p) * 8;
            const int row = flat >> 6, col = flat & 63;
            GLOAD_LDS(x16 + (size_t)(g0 + row) * Dz + k0 + col, &As[flat]);
            GLOAD_LDS(w16 + (size_t)(n0 + row) * Dz + k0 + col, &Bs[flat]);
        }
        __syncthreads();
        #pragma unroll
        for (int ks = 0; ks < 2; ++ks) {
            const int kk = ks * 32 + kq * 8;
            half8 a[4], b[4];
            #pragma unroll
            for (int i = 0; i < 4; ++i) a[i] = *(const half8*)&As[(wm + i * 16 + fr) * 64 + kk];
            #pragma unroll
            for (int j = 0; j < 4; ++j) b[j] = *(const half8*)&Bs[(wn + j * 16 + fr) * 64 + kk];
            #pragma unroll
            for (int i = 0; i < 4; ++i)
                #pragma unroll
                for (int j = 0; j < 4; ++j)
                    acc[i][j] = __builtin_amdgcn_mfma_f32_16x16x32_f16(a[i], b[j], acc[i][j], 0, 0, 0);
        }
    }

    // Epilogue. C layout: col=lane&15 (n side), row=kq*4+reg (m side).
    // theta is block-uniform: cols of this block sit entirely in one half.
    const int qside = (by < 2);
    const float* bias = qside ? bq : bv;
    _Float16* outp = qside ? xq : xv;
    const float theta = (by & 1) ? 1e-4f : 1.0f;
    const float sign  = (fr & 1) ? 1.0f : -1.0f;

    float sn[4][4], cs[4][4];
    #pragma unroll
    for (int i = 0; i < 4; ++i)
        #pragma unroll
        for (int r = 0; r < 4; ++r) {
            const int g = g0 + wm + i * 16 + kq * 4 + r;
            const float pos = (float)((g & (Sz - 1)) + 1);
            __sincosf(pos * theta, &sn[i][r], &cs[i][r]);
        }

    #pragma unroll
    for (int j = 0; j < 4; ++j) {
        const int ch = (by & 1) * 128 + wn + j * 16 + fr;   // col within 256
        const float bcol = bias[ch];
        #pragma unroll
        for (int i = 0; i < 4; ++i)
            #pragma unroll
            for (int r = 0; r < 4; ++r) {
                const int g = g0 + wm + i * 16 + kq * 4 + r;
                float v = acc[i][j][r] + bcol;
                float other = __shfl_xor(v, 1, 64);   // pair partner col ch^1
                outp[(size_t)g * Dz + ch] =
                    (_Float16)(v * sn[i][r] + sign * other * cs[i][r]);
            }
    }
}

// ---------------------------------------------------------------------------
// K2 (fused, round-3 arithmetic): one block per (b,h).
// Phase 1: loop 8 s-chunks of 128; per chunk stage [16][136] transposed tiles
//          (R3 head_outer staging), thread (e,f) accumulates fp32 scalar dot.
// Phase 2: Ms in LDS -> per-thread P column (R3 make_p verbatim).
// ---------------------------------------------------------------------------
__global__ __launch_bounds__(256) void headm_p(
    const _Float16* __restrict__ xq, const _Float16* __restrict__ xv,
    const float* __restrict__ Wo, _Float16* __restrict__ Pt)
{
    __shared__ __align__(16) _Float16 qsT[16][136];
    __shared__ __align__(16) _Float16 vsT[16][136];
    __shared__ float Ms[256];
    const int t = threadIdx.x;
    const int bh = blockIdx.x;
    const int b = bh >> 4, h = bh & 15;
    const size_t base0 = (size_t)b * Sz * Dz + h * 16;

    const int e = t >> 4, f = t & 15;
    float acc = 0.f;

    for (int chunk = 0; chunk < 8; ++chunk) {
        const size_t base = base0 + (size_t)chunk * 128 * Dz;
        __syncthreads();   // previous iteration's reads done before restage
        {
            const int s = t >> 1, eg = t & 1;
            half8 q8 = *(const half8*)&xq[base + (size_t)s * Dz + eg * 8];
            half8 v8 = *(const half8*)&xv[base + (size_t)s * Dz + eg * 8];
            #pragma unroll
            for (int i = 0; i < 8; ++i) {
                qsT[eg * 8 + i][s] = q8[i];
                vsT[eg * 8 + i][s] = v8[i];
            }
        }
        __syncthreads();
        #pragma unroll
        for (int s0 = 0; s0 < 128; s0 += 8) {
            half8 q8 = *(const half8*)&qsT[e][s0];
            half8 v8 = *(const half8*)&vsT[f][s0];
            #pragma unroll
            for (int i = 0; i < 8; ++i) acc += (float)q8[i] * (float)v8[i];
        }
    }

    __syncthreads();
    Ms[t] = acc * 0.25f;     // Ms[e*16+f]
    __syncthreads();

    // Phase 2 (R3 make_p): thread t = output column c.
    const int c = t;
    float wo[16];
    const float4* wop = (const float4*)&Wo[(size_t)c * Dz + h * 16];
    #pragma unroll
    for (int q = 0; q < 4; ++q) {
        float4 v = wop[q];
        wo[4*q+0] = v.x; wo[4*q+1] = v.y; wo[4*q+2] = v.z; wo[4*q+3] = v.w;
    }
    half8 lo, hi;
    #pragma unroll
    for (int ee = 0; ee < 16; ++ee) {
        float a = 0.f;
        #pragma unroll
        for (int ff = 0; ff < 16; ++ff) a = fmaf(Ms[ee * 16 + ff], wo[ff], a);
        if (ee < 8) lo[ee] = (_Float16)a; else hi[ee - 8] = (_Float16)a;
    }
    _Float16* dst = &Pt[((size_t)(b * 256 + c)) * Dz + h * 16];
    *(half8*)dst       = lo;
    *(half8*)(dst + 8) = hi;
}

// ---------------------------------------------------------------------------
// K3: out[g][c] = sum_r xq16[g][r] * Pt[b][c][r] + bo[c], fp32 out.
// 64x128 tile, BK=64, grid (128,2). (verbatim from the round-3 PASSED kernel)
// ---------------------------------------------------------------------------
__global__ __launch_bounds__(256) void out_gemm(
    const _Float16* __restrict__ xq, const _Float16* __restrict__ Pt,
    const float* __restrict__ bo, float* __restrict__ out)
{
    __shared__ _Float16 As[64 * 64];
    __shared__ _Float16 Bs[128 * 64];
    const int t = threadIdx.x, lane = t & 63, w = t >> 6;
    const int g0 = blockIdx.x * 64;
    const int n0 = blockIdx.y * 128;
    const int b  = g0 >> 10;
    const int wm = (w >> 1) * 32, wn = (w & 1) * 64;
    const int fr = lane & 15, kq = lane >> 4;
    const _Float16* Pb = Pt + (size_t)b * 256 * Dz;

    floatx4 acc[2][4] = {};

    for (int k0 = 0; k0 < Dz; k0 += 64) {
        __syncthreads();
        #pragma unroll
        for (int p = 0; p < 2; ++p) {
            const int flat = (t + 256 * p) * 8;
            const int row = flat >> 6, col = flat & 63;
            GLOAD_LDS(xq + (size_t)(g0 + row) * Dz + k0 + col, &As[flat]);
        }
        #pragma unroll
        for (int p = 0; p < 4; ++p) {
            const int flat = (t + 256 * p) * 8;
            const int row = flat >> 6, col = flat & 63;
            GLOAD_LDS(Pb + (size_t)(n0 + row) * Dz + k0 + col, &Bs[flat]);
        }
        __syncthreads();
        #pragma unroll
        for (int ks = 0; ks < 2; ++ks) {
            const int kk = ks * 32 + kq * 8;
            half8 a[2], bf[4];
            #pragma unroll
            for (int i = 0; i < 2; ++i) a[i] = *(const half8*)&As[(wm + i * 16 + fr) * 64 + kk];
            #pragma unroll
            for (int j = 0; j < 4; ++j) bf[j] = *(const half8*)&Bs[(wn + j * 16 + fr) * 64 + kk];
            #pragma unroll
            for (int i = 0; i < 2; ++i)
                #pragma unroll
                for (int j = 0; j < 4; ++j)
                    acc[i][j] = __builtin_amdgcn_mfma_f32_16x16x32_f16(a[i], bf[j], acc[i][j], 0, 0, 0);
        }
    }

    #pragma unroll
    for (int j = 0; j < 4; ++j) {
        const int c = n0 + wn + j * 16 + fr;
        const float bcol = bo[c];
        #pragma unroll
        for (int i = 0; i < 2; ++i)
            #pragma unroll
            for (int r = 0; r < 4; ++r) {
                const int g = g0 + wm + i * 16 + kq * 4 + r;
                out[(size_t)g * Dz + c] = acc[i][j][r] + bcol;
            }
    }
}

// ---------------------------------------------------------------------------
extern "C" void kernel_launch(void* const* d_in, const int* in_sizes, int n_in,
                              void* d_out, int out_size, void* d_ws, size_t ws_size,
                              hipStream_t stream)
{
    const float* x    = (const float*)d_in[0];
    const float* wq_w = (const float*)d_in[1];
    const float* wq_b = (const float*)d_in[2];
    // d_in[3], d_in[4] = wk_w, wk_b : dead in the no-cache reference path
    const float* wv_w = (const float*)d_in[5];
    const float* wv_b = (const float*)d_in[6];
    const float* wo_w = (const float*)d_in[7];
    const float* wo_b = (const float*)d_in[8];

    _Float16* x16  = (_Float16*)d_ws;                    // 2M halfs
    _Float16* w16  = x16  + (size_t)Gz * Dz;             // 131072 halfs
    _Float16* xq16 = w16  + 131072;                      // 2M halfs
    _Float16* xv16 = xq16 + (size_t)Gz * Dz;             // 2M halfs
    _Float16* Pt   = xv16 + (size_t)Gz * Dz;             // 524288 halfs
    float*    out  = (float*)d_out;

    convert_kernel<<<dim3((Gz * Dz + 131072) / 2048), 256, 0, stream>>>(
        x, wq_w, wv_w, x16, w16);
    qv_gemm_rope<<<dim3(Gz / 128, 4), 256, 0, stream>>>(
        x16, w16, wq_b, wv_b, xq16, xv16);
    headm_p<<<dim3(128), 256, 0, stream>>>(xq16, xv16, wo_w, Pt);
    out_gemm<<<dim3(Gz / 64, 2), 256, 0, stream>>>(xq16, Pt, wo_b, out);
}

// Round 6
// 103.103 us; speedup vs baseline: 1.0260x; 1.0260x over previous
//
#include <hip/hip_runtime.h>

// B=8, S=1024, D=256, H=16, HD=16. Rows G = B*S = 8192.
#define Gz 8192
#define Dz 256
#define Sz 1024

typedef _Float16 half8 __attribute__((ext_vector_type(8)));
typedef float    floatx4 __attribute__((ext_vector_type(4)));

// width-16 async global->LDS (LDS dest must be wave-uniform base + lane*16)
#define GLOAD_LDS(gptr, lptr)                                                      \
    __builtin_amdgcn_global_load_lds(                                              \
        (const __attribute__((address_space(1))) void*)(gptr),                     \
        (__attribute__((address_space(3))) void*)(lptr), 16, 0, 0)

__device__ inline half8 cvt8(const float* __restrict__ p) {
    float4 a = ((const float4*)p)[0];
    float4 b = ((const float4*)p)[1];
    half8 h;
    h[0]=(_Float16)a.x; h[1]=(_Float16)a.y; h[2]=(_Float16)a.z; h[3]=(_Float16)a.w;
    h[4]=(_Float16)b.x; h[5]=(_Float16)b.y; h[6]=(_Float16)b.z; h[7]=(_Float16)b.w;
    return h;
}

// ---------------------------------------------------------------------------
// K0: x -> fp16 x16 [8192x256]; pack [Wq;Wv] -> fp16 w16 [512x256].
// ---------------------------------------------------------------------------
__global__ __launch_bounds__(256) void convert_kernel(
    const float* __restrict__ x, const float* __restrict__ wq,
    const float* __restrict__ wv,
    _Float16* __restrict__ x16, _Float16* __restrict__ w16)
{
    size_t e = ((size_t)blockIdx.x * 256 + threadIdx.x) * 8;
    const float* src;
    _Float16* dst;
    if (e < (size_t)Gz * Dz) { src = x + e; dst = x16 + e; }
    else {
        size_t e2 = e - (size_t)Gz * Dz;        // 0 .. 131071
        dst = w16 + e2;
        src = (e2 < 65536) ? (wq + e2) : (wv + (e2 - 65536));
    }
    *(half8*)dst = cvt8(src);
}

// ---------------------------------------------------------------------------
// K1: C[8192x512] = x16 @ w16^T, +bias, RoPE, fp16 -> xq (by<2) / xv (by>=2).
// 128x128 tile, BK=64, global_load_lds width16, 4 waves each 64x64.
// ---------------------------------------------------------------------------
__global__ __launch_bounds__(256) void qv_gemm_rope(
    const _Float16* __restrict__ x16, const _Float16* __restrict__ w16,
    const float* __restrict__ bq, const float* __restrict__ bv,
    _Float16* __restrict__ xq, _Float16* __restrict__ xv)
{
    __shared__ _Float16 As[128 * 64];   // unpadded: global_load_lds layout
    __shared__ _Float16 Bs[128 * 64];
    const int t = threadIdx.x, lane = t & 63, w = t >> 6;
    const int g0 = blockIdx.x * 128;
    const int by = blockIdx.y;              // 0..3 -> cols [by*128, +128)
    const int n0 = by * 128;
    const int wm = (w >> 1) * 64, wn = (w & 1) * 64;
    const int fr = lane & 15, kq = lane >> 4;

    floatx4 acc[4][4] = {};

    for (int k0 = 0; k0 < Dz; k0 += 64) {
        __syncthreads();
        #pragma unroll
        for (int p = 0; p < 4; ++p) {
            const int flat = (t + 256 * p) * 8;
            const int row = flat >> 6, col = flat & 63;
            GLOAD_LDS(x16 + (size_t)(g0 + row) * Dz + k0 + col, &As[flat]);
            GLOAD_LDS(w16 + (size_t)(n0 + row) * Dz + k0 + col, &Bs[flat]);
        }
        __syncthreads();
        #pragma unroll
        for (int ks = 0; ks < 2; ++ks) {
            const int kk = ks * 32 + kq * 8;
            half8 a[4], b[4];
            #pragma unroll
            for (int i = 0; i < 4; ++i) a[i] = *(const half8*)&As[(wm + i * 16 + fr) * 64 + kk];
            #pragma unroll
            for (int j = 0; j < 4; ++j) b[j] = *(const half8*)&Bs[(wn + j * 16 + fr) * 64 + kk];
            #pragma unroll
            for (int i = 0; i < 4; ++i)
                #pragma unroll
                for (int j = 0; j < 4; ++j)
                    acc[i][j] = __builtin_amdgcn_mfma_f32_16x16x32_f16(a[i], b[j], acc[i][j], 0, 0, 0);
        }
    }

    // Epilogue. C layout: col=lane&15 (n side), row=kq*4+reg (m side).
    // theta is block-uniform: cols of this block sit entirely in one half.
    const int qside = (by < 2);
    const float* bias = qside ? bq : bv;
    _Float16* outp = qside ? xq : xv;
    const float theta = (by & 1) ? 1e-4f : 1.0f;
    const float sign  = (fr & 1) ? 1.0f : -1.0f;

    float sn[4][4], cs[4][4];
    #pragma unroll
    for (int i = 0; i < 4; ++i)
        #pragma unroll
        for (int r = 0; r < 4; ++r) {
            const int g = g0 + wm + i * 16 + kq * 4 + r;
            const float pos = (float)((g & (Sz - 1)) + 1);
            __sincosf(pos * theta, &sn[i][r], &cs[i][r]);
        }

    #pragma unroll
    for (int j = 0; j < 4; ++j) {
        const int ch = (by & 1) * 128 + wn + j * 16 + fr;   // col within 256
        const float bcol = bias[ch];
        #pragma unroll
        for (int i = 0; i < 4; ++i)
            #pragma unroll
            for (int r = 0; r < 4; ++r) {
                const int g = g0 + wm + i * 16 + kq * 4 + r;
                float v = acc[i][j][r] + bcol;
                float other = __shfl_xor(v, 1, 64);   // pair partner col ch^1
                outp[(size_t)g * Dz + ch] =
                    (_Float16)(v * sn[i][r] + sign * other * cs[i][r]);
            }
    }
}

// ---------------------------------------------------------------------------
// K2: split-K head outer products. Mpart[chunk][bh][e*16+f] =
//     sum_{s in chunk} xq[b,s,h16+e]*xv[b,s,h16+f]. No atomics.
// ---------------------------------------------------------------------------
__global__ __launch_bounds__(256) void head_outer(
    const _Float16* __restrict__ xq, const _Float16* __restrict__ xv,
    float* __restrict__ Mpart)
{
    __shared__ __align__(16) _Float16 qsT[16][136];
    __shared__ __align__(16) _Float16 vsT[16][136];
    const int t = threadIdx.x;
    const int bh = blockIdx.x;
    const int b = bh >> 4, h = bh & 15;
    const size_t base = (size_t)b * Sz * Dz + (size_t)blockIdx.y * 128 * Dz + h * 16;

    {
        const int s = t >> 1, eg = t & 1;
        half8 q8 = *(const half8*)&xq[base + (size_t)s * Dz + eg * 8];
        half8 v8 = *(const half8*)&xv[base + (size_t)s * Dz + eg * 8];
        #pragma unroll
        for (int i = 0; i < 8; ++i) {
            qsT[eg * 8 + i][s] = q8[i];
            vsT[eg * 8 + i][s] = v8[i];
        }
    }
    __syncthreads();

    const int e = t >> 4, f = t & 15;
    float acc = 0.f;
    #pragma unroll
    for (int s0 = 0; s0 < 128; s0 += 8) {
        half8 q8 = *(const half8*)&qsT[e][s0];
        half8 v8 = *(const half8*)&vsT[f][s0];
        #pragma unroll
        for (int i = 0; i < 8; ++i) acc += (float)q8[i] * (float)v8[i];
    }
    Mpart[((size_t)blockIdx.y * 128 + bh) * 256 + t] = acc;
}

// ---------------------------------------------------------------------------
// KP: Pt[b][c][h16+e] = fp16( 0.25 * sum_f M[b,h][e][f] * Wo[c][h16+f] )
// ---------------------------------------------------------------------------
__global__ __launch_bounds__(256) void make_p(
    const float* __restrict__ Mpart, const float* __restrict__ Wo,
    _Float16* __restrict__ Pt)
{
    __shared__ float Ms[256];
    const int t = threadIdx.x;
    const int bh = blockIdx.x;
    const int b = bh >> 4, h = bh & 15;
    float s = 0.f;
    #pragma unroll
    for (int c = 0; c < 8; ++c) s += Mpart[((size_t)c * 128 + bh) * 256 + t];
    Ms[t] = s * 0.25f;
    __syncthreads();

    const int c = t;
    float wo[16];
    const float4* wop = (const float4*)&Wo[(size_t)c * Dz + h * 16];
    #pragma unroll
    for (int q = 0; q < 4; ++q) {
        float4 v = wop[q];
        wo[4*q+0] = v.x; wo[4*q+1] = v.y; wo[4*q+2] = v.z; wo[4*q+3] = v.w;
    }
    half8 lo, hi;
    #pragma unroll
    for (int e = 0; e < 16; ++e) {
        float a = 0.f;
        #pragma unroll
        for (int f = 0; f < 16; ++f) a = fmaf(Ms[e * 16 + f], wo[f], a);
        if (e < 8) lo[e] = (_Float16)a; else hi[e - 8] = (_Float16)a;
    }
    _Float16* dst = &Pt[((size_t)(b * 256 + c)) * Dz + h * 16];
    *(half8*)dst       = lo;
    *(half8*)(dst + 8) = hi;
}

// ---------------------------------------------------------------------------
// K3: out[g][c] = sum_r xq16[g][r] * Pt[b][c][r] + bo[c], fp32 out.
// 64x128 tile, BK=64, grid (128,2) = 256 blocks. Waves each 32x64.
// ---------------------------------------------------------------------------
__global__ __launch_bounds__(256) void out_gemm(
    const _Float16* __restrict__ xq, const _Float16* __restrict__ Pt,
    const float* __restrict__ bo, float* __restrict__ out)
{
    __shared__ _Float16 As[64 * 64];
    __shared__ _Float16 Bs[128 * 64];
    const int t = threadIdx.x, lane = t & 63, w = t >> 6;
    const int g0 = blockIdx.x * 64;
    const int n0 = blockIdx.y * 128;
    const int b  = g0 >> 10;
    const int wm = (w >> 1) * 32, wn = (w & 1) * 64;
    const int fr = lane & 15, kq = lane >> 4;
    const _Float16* Pb = Pt + (size_t)b * 256 * Dz;

    floatx4 acc[2][4] = {};

    for (int k0 = 0; k0 < Dz; k0 += 64) {
        __syncthreads();
        #pragma unroll
        for (int p = 0; p < 2; ++p) {
            const int flat = (t + 256 * p) * 8;
            const int row = flat >> 6, col = flat & 63;
            GLOAD_LDS(xq + (size_t)(g0 + row) * Dz + k0 + col, &As[flat]);
        }
        #pragma unroll
        for (int p = 0; p < 4; ++p) {
            const int flat = (t + 256 * p) * 8;
            const int row = flat >> 6, col = flat & 63;
            GLOAD_LDS(Pb + (size_t)(n0 + row) * Dz + k0 + col, &Bs[flat]);
        }
        __syncthreads();
        #pragma unroll
        for (int ks = 0; ks < 2; ++ks) {
            const int kk = ks * 32 + kq * 8;
            half8 a[2], bf[4];
            #pragma unroll
            for (int i = 0; i < 2; ++i) a[i] = *(const half8*)&As[(wm + i * 16 + fr) * 64 + kk];
            #pragma unroll
            for (int j = 0; j < 4; ++j) bf[j] = *(const half8*)&Bs[(wn + j * 16 + fr) * 64 + kk];
            #pragma unroll
            for (int i = 0; i < 2; ++i)
                #pragma unroll
                for (int j = 0; j < 4; ++j)
                    acc[i][j] = __builtin_amdgcn_mfma_f32_16x16x32_f16(a[i], bf[j], acc[i][j], 0, 0, 0);
        }
    }

    #pragma unroll
    for (int j = 0; j < 4; ++j) {
        const int c = n0 + wn + j * 16 + fr;
        const float bcol = bo[c];
        #pragma unroll
        for (int i = 0; i < 2; ++i)
            #pragma unroll
            for (int r = 0; r < 4; ++r) {
                const int g = g0 + wm + i * 16 + kq * 4 + r;
                out[(size_t)g * Dz + c] = acc[i][j][r] + bcol;
            }
    }
}

// ---------------------------------------------------------------------------
extern "C" void kernel_launch(void* const* d_in, const int* in_sizes, int n_in,
                              void* d_out, int out_size, void* d_ws, size_t ws_size,
                              hipStream_t stream)
{
    const float* x    = (const float*)d_in[0];
    const float* wq_w = (const float*)d_in[1];
    const float* wq_b = (const float*)d_in[2];
    // d_in[3], d_in[4] = wk_w, wk_b : dead in the no-cache reference path
    const float* wv_w = (const float*)d_in[5];
    const float* wv_b = (const float*)d_in[6];
    const float* wo_w = (const float*)d_in[7];
    const float* wo_b = (const float*)d_in[8];

    _Float16* x16  = (_Float16*)d_ws;                    // 2M halfs
    _Float16* w16  = x16  + (size_t)Gz * Dz;             // 131072 halfs
    _Float16* xq16 = w16  + 131072;                      // 2M halfs
    _Float16* xv16 = xq16 + (size_t)Gz * Dz;             // 2M halfs
    _Float16* Pt   = xv16 + (size_t)Gz * Dz;             // 524288 halfs
    float*    Mpart = (float*)(Pt + 524288);             // 8*128*256 floats
    float*    out  = (float*)d_out;

    convert_kernel<<<dim3((Gz * Dz + 131072) / 2048), 256, 0, stream>>>(
        x, wq_w, wv_w, x16, w16);
    qv_gemm_rope<<<dim3(Gz / 128, 4), 256, 0, stream>>>(
        x16, w16, wq_b, wv_b, xq16, xv16);
    head_outer<<<dim3(128, 8), 256, 0, stream>>>(xq16, xv16, Mpart);
    make_p<<<dim3(128), 256, 0, stream>>>(Mpart, wo_w, Pt);
    out_gemm<<<dim3(Gz / 64, 2), 256, 0, stream>>>(xq16, Pt, wo_b, out);
}